// Round 7
// baseline (352.041 us; speedup 1.0000x reference)
//
#include <hip/hip_runtime.h>
#include <stdint.h>

#define NNODES 32768
#define NREL 10
#define NBASES 4
#define DIM 256
#define NEDGE 524288
#define KW 1280                 /* 4*256 basis + 256 root */
#define KBASE 1024              /* z width */

#define HB 2048                 /* hist blocks  */
#define CB 8192                 /* conv blocks  */
#define WB 80                   /* build_wt blocks per layer (20 k x 4 n) */

typedef __attribute__((ext_vector_type(8))) short bf16x8;
typedef __attribute__((ext_vector_type(4))) float f32x4;
typedef __attribute__((ext_vector_type(2))) float f32x2;

__device__ __forceinline__ float bf2f(unsigned short u){
  union { unsigned int i; float f; } v; v.i = ((unsigned int)u) << 16; return v.f;
}
__device__ __forceinline__ float asf(unsigned int u){
  union { unsigned int i; float f; } v; v.i = u; return v.f;
}
__device__ __forceinline__ unsigned short f2bf(float f){
  union { float f; unsigned int i; } v; v.f = f;
  unsigned int x = v.i;
  unsigned int r = (x + 0x7FFFu + ((x >> 16) & 1u)) >> 16;
  return (unsigned short)r;
}
__device__ __forceinline__ void gll16(const void* g, void* l){
  __builtin_amdgcn_global_load_lds((const __attribute__((address_space(1))) void*)g,
                                   (__attribute__((address_space(3))) void*)l, 16, 0, 0);
}

// ---- mega: fused independent prep  (hist | conv fp32->bf16 | build Wt0,Wt1)
__global__ __launch_bounds__(256) void mega_prep(
    const int* __restrict__ ec, const int* __restrict__ rel,
    int* __restrict__ cnt_rd,
    const float* __restrict__ x, unsigned short* __restrict__ Xh,
    const float* __restrict__ basis0, const float* __restrict__ root0,
    unsigned short* __restrict__ Wt0,
    const float* __restrict__ basis1, const float* __restrict__ root1,
    unsigned short* __restrict__ Wt1)
{
  __shared__ float tile[64][65];
  int bid = blockIdx.x;
  int t = threadIdx.x;
  if (bid < HB){
    // ---- histogram over (rel, dst)
    int e = bid * 256 + t;
    int d = ec[NEDGE + e];
    int r = rel[e];
    atomicAdd(&cnt_rd[(r << 15) + d], 1);
  } else if (bid < HB + CB){
    // ---- x fp32 -> bf16
    int i = (bid - HB) * 256 + t;
    float4 v = ((const float4*)x)[i];
    ushort4 o; o.x = f2bf(v.x); o.y = f2bf(v.y); o.z = f2bf(v.z); o.w = f2bf(v.w);
    ((ushort4*)Xh)[i] = o;
  } else {
    // ---- build Wt[n][k] = stacked [basis;root]^T via LDS transpose
    int b = bid - HB - CB;
    int layer = b / WB; b %= WB;
    const float* basis = layer ? basis1 : basis0;
    const float* root  = layer ? root1  : root0;
    unsigned short* Wt = layer ? Wt1    : Wt0;
    int k0 = (b % 20) * 64;
    int n0 = (b / 20) * 64;
    int tn = t & 63, tk = t >> 6;
#pragma unroll
    for (int i = 0; i < 64; i += 4){
      int k = k0 + tk + i;
      float v = (k < KBASE) ? basis[(size_t)k * 256 + n0 + tn]
                            : root[(size_t)(k - KBASE) * 256 + n0 + tn];
      tile[tk + i][tn] = v;
    }
    __syncthreads();
#pragma unroll
    for (int i = 0; i < 64; i += 4){
      int n = n0 + tk + i;
      Wt[(size_t)n * KW + k0 + tn] = f2bf(tile[tn][tk + i]);
    }
  }
}

// ---------------- scan: phase 1 (local excl scan + blocksums), phase 2 fused
__global__ __launch_bounds__(1024) void scan1(const int* __restrict__ cnt_rd,
                                              int* __restrict__ offs, int* __restrict__ blksum)
{
  __shared__ int sh[1024];
  int tid = threadIdx.x; int gid = blockIdx.x * 1024 + tid;
  int v = 0;
#pragma unroll
  for (int r = 0; r < NREL; r++) v += cnt_rd[(r << 15) + gid];
  sh[tid] = v; __syncthreads();
  for (int off = 1; off < 1024; off <<= 1){
    int t = (tid >= off) ? sh[tid - off] : 0;
    __syncthreads(); sh[tid] += t; __syncthreads();
  }
  offs[gid] = sh[tid] - v;
  if (tid == 1023) blksum[blockIdx.x] = sh[1023];
}
// scan3b: fold old scan2 into scan3 — each block redundantly reduces the 32
// raw block sums for j < blockIdx.x (wave-0 shuffle reduce), saves a dispatch.
__global__ __launch_bounds__(1024) void scan3b(int* __restrict__ offs, const int* __restrict__ blksum)
{
  __shared__ int pre;
  int bid = blockIdx.x;
  if (threadIdx.x < 64){
    int v = ((int)threadIdx.x < bid && threadIdx.x < 32) ? blksum[threadIdx.x] : 0;
#pragma unroll
    for (int o = 1; o < 64; o <<= 1) v += __shfl_xor(v, o);
    if (threadIdx.x == 0) pre = v;
  }
  __syncthreads();
  int gid = bid * 1024 + threadIdx.x;
  offs[gid] += pre;
  if (gid == 0) offs[NNODES] = NEDGE;
}

// --------------------------- bucket scatter: sort by dst, pack (src<<4 | r)
__global__ void scatter_kernel(const int* __restrict__ ec, const int* __restrict__ rel,
                               const int* __restrict__ offs, int* __restrict__ cursor,
                               unsigned int* __restrict__ meta)
{
  int e = blockIdx.x * 256 + threadIdx.x;
  int s = ec[e];
  int d = ec[NEDGE + e];
  int r = rel[e];
  int p = offs[d] + atomicAdd(&cursor[d], 1);
  meta[p] = ((unsigned int)s << 4) | (unsigned int)r;
}

// --------- fused comp-weighted segment sums; per-dst LDS weight table
// agg8 = 8 hoisted gather chains, predicated 4-edge tail, packed f32x2
// arithmetic (v_pk_fma_f32), 32-bit gather offsets. [frozen from round 3]
__global__ __launch_bounds__(256) void agg8(
    const unsigned short* __restrict__ Xin,   // [N,256] bf16
    const int* __restrict__ offs,             // [N+1]
    const unsigned int* __restrict__ meta,    // packed src<<4|r
    const float* __restrict__ comp,           // [NREL*NBASES] fp32
    const int* __restrict__ cnt_rd,           // [NREL, N]
    unsigned short* __restrict__ z)           // [N, KBASE] bf16
{
  __shared__ __attribute__((aligned(16))) float wtab[4][40];  // [wave][r*4+b]
  int t = threadIdx.x;
  int wv = t >> 6, lane = t & 63;
  int d = blockIdx.x * 4 + wv;
  if (lane < 40){
    int r = lane >> 2, b = lane & 3;
    int cnt = cnt_rd[(r << 15) + d];
    wtab[wv][lane] = (cnt > 0) ? comp[r * NBASES + b] / (float)cnt : 0.0f;
  }
  __syncthreads();

  const float4* wt4 = (const float4*)&wtab[wv][0];   // indexed by r
  const char* Xb = (const char*)Xin;
  unsigned colb = (unsigned)(lane * 8);              // byte offset of this lane's 4 cols

  // acc[b][0] = (col0,col1), acc[b][1] = (col2,col3)
  f32x2 acc[NBASES][2];
#pragma unroll
  for (int b = 0; b < NBASES; b++){ acc[b][0] = (f32x2){0.f,0.f}; acc[b][1] = (f32x2){0.f,0.f}; }

  int e0 = offs[d], e1 = offs[d + 1];
  int e = e0;

  // ---- main: 8 edges per iteration, all gathers issued before consumption
  for (; e + 7 < e1; e += 8){
    unsigned int m[8];
#pragma unroll
    for (int i = 0; i < 8; i++) m[i] = meta[e + i];
    uint2 v[8];
#pragma unroll
    for (int i = 0; i < 8; i++){
      unsigned off = ((m[i] & 0xFFFFFFF0u) << 5) + colb;   // (src*512) + lane*8
      v[i] = *(const uint2*)(Xb + off);
    }
#pragma unroll
    for (int i = 0; i < 8; i++){
      float4 w = wt4[m[i] & 15u];
      f32x2 f01, f23;
      f01.x = asf(v[i].x << 16); f01.y = asf(v[i].x & 0xffff0000u);
      f23.x = asf(v[i].y << 16); f23.y = asf(v[i].y & 0xffff0000u);
      acc[0][0] += (f32x2){w.x, w.x} * f01;  acc[0][1] += (f32x2){w.x, w.x} * f23;
      acc[1][0] += (f32x2){w.y, w.y} * f01;  acc[1][1] += (f32x2){w.y, w.y} * f23;
      acc[2][0] += (f32x2){w.z, w.z} * f01;  acc[2][1] += (f32x2){w.z, w.z} * f23;
      acc[3][0] += (f32x2){w.w, w.w} * f01;  acc[3][1] += (f32x2){w.w, w.w} * f23;
    }
  }

  // ---- tail: predicated 4-edge groups (invalid edges: w=0, index clamped)
  for (; e < e1; e += 4){
    unsigned int m[4];
    float4 w[4];
#pragma unroll
    for (int i = 0; i < 4; i++){
      int ei = e + i;
      bool ok = ei < e1;
      m[i] = meta[ok ? ei : e1 - 1];
      float4 ww = wt4[m[i] & 15u];
      if (!ok){ ww.x = 0.f; ww.y = 0.f; ww.z = 0.f; ww.w = 0.f; }
      w[i] = ww;
    }
    uint2 v[4];
#pragma unroll
    for (int i = 0; i < 4; i++){
      unsigned off = ((m[i] & 0xFFFFFFF0u) << 5) + colb;
      v[i] = *(const uint2*)(Xb + off);
    }
#pragma unroll
    for (int i = 0; i < 4; i++){
      f32x2 f01, f23;
      f01.x = asf(v[i].x << 16); f01.y = asf(v[i].x & 0xffff0000u);
      f23.x = asf(v[i].y << 16); f23.y = asf(v[i].y & 0xffff0000u);
      acc[0][0] += (f32x2){w[i].x, w[i].x} * f01;  acc[0][1] += (f32x2){w[i].x, w[i].x} * f23;
      acc[1][0] += (f32x2){w[i].y, w[i].y} * f01;  acc[1][1] += (f32x2){w[i].y, w[i].y} * f23;
      acc[2][0] += (f32x2){w[i].z, w[i].z} * f01;  acc[2][1] += (f32x2){w[i].z, w[i].z} * f23;
      acc[3][0] += (f32x2){w[i].w, w[i].w} * f01;  acc[3][1] += (f32x2){w[i].w, w[i].w} * f23;
    }
  }

#pragma unroll
  for (int b = 0; b < NBASES; b++){
    ushort4 o;
    o.x = f2bf(acc[b][0].x); o.y = f2bf(acc[b][0].y);
    o.z = f2bf(acc[b][1].x); o.w = f2bf(acc[b][1].y);
    *(ushort4*)(z + (size_t)d * KBASE + b * 256 + lane * 4) = o;
  }
}

// ---- MFMA GEMM v8: Y[M,256] = [z | ext] @ Wt^T + bias  (tile 64m x 256n)
// gemm4 skeleton (2 __syncthreads/step, compiler-scheduled, no inline asm)
// with the LDS-port bottleneck removed:
//  * B DIRECT from global to registers (Wt is 0.66 MB, L2-resident; fragment
//    is a natural 16B/lane load; no duplication within a block). Kills the
//    16KB Bs buffer: ~2/3 of LDS port traffic + 4 of 5 gll16s per thread.
//  * BK=64 (As = 64x64 = 8 KB single buffer) -> 20 K-steps, half the barriers.
// B loads issue beside the A-stage; the existing barrier's vmcnt(0) drain
// makes them MFMA-ready with no extra wait.
// A staging: pre-swizzled global source, linear LDS dst (m173 pattern),
// 8 k-slots: granule (row,kc) lives at slot (kc + (row>>1)) & 7.
// mode 1: outh = relu(v) bf16 ; mode 2: outf = v fp32
__global__ __launch_bounds__(256) void gemm8(
    const unsigned short* __restrict__ A0,   // z [M,KBASE]
    const unsigned short* __restrict__ A1,   // ext [M,256]
    const unsigned short* __restrict__ Wt,   // [256,KW]
    const float* __restrict__ bias,
    unsigned short* __restrict__ outh,
    float* __restrict__ outf,
    int mode)
{
  __shared__ __attribute__((aligned(16))) short As[64 * 64];    // 8 KB
  int tid  = threadIdx.x;
  int m0   = blockIdx.x * 64;
  int lane = tid & 63;
  int wn   = tid >> 6;               // wave = n-slice 0..3 (64 cols each)
  int lq = lane >> 4, lr = lane & 15;

  f32x4 zero = {0.f, 0.f, 0.f, 0.f};
  f32x4 acc[4][4];
#pragma unroll
  for (int i = 0; i < 4; i++)
#pragma unroll
    for (int j = 0; j < 4; j++) acc[i][j] = zero;

  // A staging source params: granules g = tid and tid+256;
  // row = g>>3, slot = g&7, kc = (slot - (row>>1)) & 7  (inverse swizzle)
  int arow0 = tid >> 3;
  int akc0  = ((tid & 7) - (tid >> 4)) & 7;
  int g1    = tid + 256;
  int arow1 = g1 >> 3;
  int akc1  = ((g1 & 7) - (g1 >> 4)) & 7;

  // B row base for this wave's n-columns (per j-fragment), per-lane
  const unsigned short* wtb[4];
#pragma unroll
  for (int j = 0; j < 4; j++)
    wtb[j] = Wt + (size_t)(wn * 64 + j * 16 + lr) * KW + lq * 8;

  for (int k0 = 0; k0 < KW; k0 += 64){
    __syncthreads();                 // prior ds_reads of As complete (full drain)
    {
      const unsigned short* ga0, *ga1;
      if (k0 < KBASE){
        ga0 = A0 + (size_t)(m0 + arow0) * KBASE + k0 + akc0 * 8;
        ga1 = A0 + (size_t)(m0 + arow1) * KBASE + k0 + akc1 * 8;
      } else {
        ga0 = A1 + (size_t)(m0 + arow0) * 256 + (k0 - KBASE) + akc0 * 8;
        ga1 = A1 + (size_t)(m0 + arow1) * 256 + (k0 - KBASE) + akc1 * 8;
      }
      gll16(ga0, As + tid * 8);            // linear LDS dst (wave-uniform + lane*16)
      gll16(ga1, As + (tid + 256) * 8);
    }
    // B fragments for this K-step, direct to VGPRs (drained by the barrier)
    bf16x8 bfr[4][2];
#pragma unroll
    for (int j = 0; j < 4; j++)
#pragma unroll
      for (int s = 0; s < 2; s++)
        bfr[j][s] = *(const bf16x8*)(wtb[j] + k0 + s * 32);
    __syncthreads();                 // As staged + B landed (vmcnt(0) drain)

    bf16x8 af[4][2];
#pragma unroll
    for (int i = 0; i < 4; i++){
      int row = i * 16 + lr;
#pragma unroll
      for (int s = 0; s < 2; s++){
        int slot = ((lq + 4 * s) + (row >> 1)) & 7;
        af[i][s] = *(const bf16x8*)(As + row * 64 + slot * 8);
      }
    }
#pragma unroll
    for (int i = 0; i < 4; i++)
#pragma unroll
      for (int j = 0; j < 4; j++){
        acc[i][j] = __builtin_amdgcn_mfma_f32_16x16x32_bf16(af[i][0], bfr[j][0], acc[i][j], 0, 0, 0);
        acc[i][j] = __builtin_amdgcn_mfma_f32_16x16x32_bf16(af[i][1], bfr[j][1], acc[i][j], 0, 0, 0);
      }
  }

  // C/D mapping: col=lane&15, row=(lane>>4)*4+reg  [m89/m91]
#pragma unroll
  for (int i = 0; i < 4; i++)
#pragma unroll
    for (int j = 0; j < 4; j++)
#pragma unroll
      for (int r = 0; r < 4; r++){
        int gm = m0 + i * 16 + lq * 4 + r;
        int gn = wn * 64 + j * 16 + lr;
        float v = acc[i][j][r] + bias[gn];
        size_t idx = (size_t)gm * 256 + gn;
        if (mode == 1) outh[idx] = f2bf(fmaxf(v, 0.f));
        else           outf[idx] = v;
      }
}

// ---------------------------------------------------------------------------
extern "C" void kernel_launch(void* const* d_in, const int* in_sizes, int n_in,
                              void* d_out, int out_size, void* d_ws, size_t ws_size,
                              hipStream_t stream)
{
  const float* x      = (const float*)d_in[0];
  const int*   ec     = (const int*)d_in[3];
  const int*   rel    = (const int*)d_in[4];
  const float* basis0 = (const float*)d_in[5];
  const float* comp0  = (const float*)d_in[6];
  const float* root0  = (const float*)d_in[7];
  const float* bias0  = (const float*)d_in[8];
  const float* basis1 = (const float*)d_in[9];
  const float* comp1  = (const float*)d_in[10];
  const float* root1  = (const float*)d_in[11];
  const float* bias1  = (const float*)d_in[12];

  char* p = (char*)d_ws;
  unsigned short* z   = (unsigned short*)p; p += (size_t)NNODES * KBASE * 2;  // 67.1 MB
  unsigned short* Xh  = (unsigned short*)p; p += (size_t)NNODES * DIM * 2;    // 16.8
  unsigned short* h   = (unsigned short*)p; p += (size_t)NNODES * DIM * 2;    // 16.8
  unsigned short* Wt0 = (unsigned short*)p; p += (size_t)256 * KW * 2;        // 0.66
  unsigned short* Wt1 = (unsigned short*)p; p += (size_t)256 * KW * 2;        // 0.66
  unsigned int* meta  = (unsigned int*)p;   p += (size_t)NEDGE * 4;           // 2.1
  int* cnt_rd  = (int*)p;   p += (size_t)NREL * NNODES * 4;                   // 1.3
  int* cursor  = (int*)p;   p += (size_t)NNODES * 4;
  int* offs    = (int*)p;   p += (size_t)(NNODES + 1) * 4;
  int* blksum  = (int*)p;   p += 1024;

  // zero cnt_rd + cursor (contiguous)
  hipMemsetAsync(cnt_rd, 0, ((size_t)NREL * NNODES + (size_t)NNODES) * 4, stream);

  // ---- fused prep: hist | conv | build Wt0 | build Wt1 ----
  mega_prep<<<HB + CB + 2 * WB, 256, 0, stream>>>(
      ec, rel, cnt_rd, x, Xh, basis0, root0, Wt0, basis1, root1, Wt1);

  scan1<<<NNODES / 1024, 1024, 0, stream>>>(cnt_rd, offs, blksum);
  scan3b<<<NNODES / 1024, 1024, 0, stream>>>(offs, blksum);
  scatter_kernel<<<NEDGE / 256, 256, 0, stream>>>(ec, rel, offs, cursor, meta);

  // ---- layer 0 ----
  agg8<<<NNODES / 4, 256, 0, stream>>>(Xh, offs, meta, comp0, cnt_rd, z);
  gemm8<<<NNODES / 64, 256, 0, stream>>>(z, Xh, Wt0, bias0, h, nullptr, 1);

  // ---- layer 1 ----
  agg8<<<NNODES / 4, 256, 0, stream>>>(h, offs, meta, comp1, cnt_rd, z);
  gemm8<<<NNODES / 64, 256, 0, stream>>>(z, h, Wt1, bias1, nullptr, (float*)d_out, 2);
}

// Round 8
// 322.322 us; speedup vs baseline: 1.0922x; 1.0922x over previous
//
#include <hip/hip_runtime.h>
#include <stdint.h>

#define NNODES 32768
#define NREL 10
#define NBASES 4
#define DIM 256
#define NEDGE 524288
#define KW 1280                 /* 4*256 basis + 256 root */
#define KBASE 1024              /* z width */

#define HB 2048                 /* hist blocks  */
#define CB 8192                 /* conv blocks  */
#define WB 80                   /* build_wt blocks per layer (20 k x 4 n) */

typedef __attribute__((ext_vector_type(8))) short bf16x8;
typedef __attribute__((ext_vector_type(4))) float f32x4;
typedef __attribute__((ext_vector_type(2))) float f32x2;

__device__ __forceinline__ float bf2f(unsigned short u){
  union { unsigned int i; float f; } v; v.i = ((unsigned int)u) << 16; return v.f;
}
__device__ __forceinline__ float asf(unsigned int u){
  union { unsigned int i; float f; } v; v.i = u; return v.f;
}
__device__ __forceinline__ unsigned short f2bf(float f){
  union { float f; unsigned int i; } v; v.f = f;
  unsigned int x = v.i;
  unsigned int r = (x + 0x7FFFu + ((x >> 16) & 1u)) >> 16;
  return (unsigned short)r;
}
__device__ __forceinline__ void gll16(const void* g, void* l){
  __builtin_amdgcn_global_load_lds((const __attribute__((address_space(1))) void*)g,
                                   (__attribute__((address_space(3))) void*)l, 16, 0, 0);
}

// ---- mega: fused independent prep  (hist | conv fp32->bf16 | build Wt0,Wt1)
__global__ __launch_bounds__(256) void mega_prep(
    const int* __restrict__ ec, const int* __restrict__ rel,
    int* __restrict__ cnt_rd,
    const float* __restrict__ x, unsigned short* __restrict__ Xh,
    const float* __restrict__ basis0, const float* __restrict__ root0,
    unsigned short* __restrict__ Wt0,
    const float* __restrict__ basis1, const float* __restrict__ root1,
    unsigned short* __restrict__ Wt1)
{
  __shared__ float tile[64][65];
  int bid = blockIdx.x;
  int t = threadIdx.x;
  if (bid < HB){
    // ---- histogram over (rel, dst)
    int e = bid * 256 + t;
    int d = ec[NEDGE + e];
    int r = rel[e];
    atomicAdd(&cnt_rd[(r << 15) + d], 1);
  } else if (bid < HB + CB){
    // ---- x fp32 -> bf16
    int i = (bid - HB) * 256 + t;
    float4 v = ((const float4*)x)[i];
    ushort4 o; o.x = f2bf(v.x); o.y = f2bf(v.y); o.z = f2bf(v.z); o.w = f2bf(v.w);
    ((ushort4*)Xh)[i] = o;
  } else {
    // ---- build Wt[n][k] = stacked [basis;root]^T via LDS transpose
    int b = bid - HB - CB;
    int layer = b / WB; b %= WB;
    const float* basis = layer ? basis1 : basis0;
    const float* root  = layer ? root1  : root0;
    unsigned short* Wt = layer ? Wt1    : Wt0;
    int k0 = (b % 20) * 64;
    int n0 = (b / 20) * 64;
    int tn = t & 63, tk = t >> 6;
#pragma unroll
    for (int i = 0; i < 64; i += 4){
      int k = k0 + tk + i;
      float v = (k < KBASE) ? basis[(size_t)k * 256 + n0 + tn]
                            : root[(size_t)(k - KBASE) * 256 + n0 + tn];
      tile[tk + i][tn] = v;
    }
    __syncthreads();
#pragma unroll
    for (int i = 0; i < 64; i += 4){
      int n = n0 + tk + i;
      Wt[(size_t)n * KW + k0 + tn] = f2bf(tile[tn][tk + i]);
    }
  }
}

// ---------------- scan phase 1: shuffle-based block-local exclusive scan
__global__ __launch_bounds__(1024) void scan1(const int* __restrict__ cnt_rd,
                                              int* __restrict__ offs, int* __restrict__ blksum)
{
  __shared__ int wsum[16];
  int tid = threadIdx.x; int gid = blockIdx.x * 1024 + tid;
  int lane = tid & 63, wv = tid >> 6;
  int v = 0;
#pragma unroll
  for (int r = 0; r < NREL; r++) v += cnt_rd[(r << 15) + gid];
  // wave-inclusive scan via shuffle
  int incl = v;
#pragma unroll
  for (int o = 1; o < 64; o <<= 1){
    int t = __shfl_up(incl, o);
    if (lane >= o) incl += t;
  }
  if (lane == 63) wsum[wv] = incl;
  __syncthreads();
  if (wv == 0){
    int s = (lane < 16) ? wsum[lane] : 0;
#pragma unroll
    for (int o = 1; o < 16; o <<= 1){
      int t = __shfl_up(s, o);
      if (lane >= o) s += t;
    }
    if (lane < 16) wsum[lane] = s;          // inclusive wave sums
  }
  __syncthreads();
  int base = wv ? wsum[wv - 1] : 0;
  offs[gid] = base + incl - v;              // block-local exclusive
  if (tid == 1023) blksum[blockIdx.x] = base + incl;   // block total
}
// scan phase 2 (fused old scan2+scan3): each block redundantly reduces the
// block sums for j < blockIdx.x via wave-0 shuffle, adds to its offs slice.
__global__ __launch_bounds__(1024) void scan3b(int* __restrict__ offs, const int* __restrict__ blksum)
{
  __shared__ int pre;
  int bid = blockIdx.x;
  if (threadIdx.x < 64){
    int v = ((int)threadIdx.x < bid && threadIdx.x < 32) ? blksum[threadIdx.x] : 0;
#pragma unroll
    for (int o = 1; o < 64; o <<= 1) v += __shfl_xor(v, o);
    if (threadIdx.x == 0) pre = v;
  }
  __syncthreads();
  int gid = bid * 1024 + threadIdx.x;
  offs[gid] += pre;
}

// ---- bucket scatter, destructive cursor: offs[d] itself is the cursor.
// Post-scatter invariant: offs[d] == original offs[d+1]  (each bucket filled
// exactly deg[d] times). agg reads e0 = offs[d-1], e1 = offs[d].
__global__ void scatter_kernel(const int* __restrict__ ec, const int* __restrict__ rel,
                               int* __restrict__ offs,
                               unsigned int* __restrict__ meta)
{
  int e = blockIdx.x * 256 + threadIdx.x;
  int s = ec[e];
  int d = ec[NEDGE + e];
  int r = rel[e];
  int p = atomicAdd(&offs[d], 1);
  meta[p] = ((unsigned int)s << 4) | (unsigned int)r;
}

// --------- fused comp-weighted segment sums; per-dst LDS weight table
// agg8 = 8 hoisted gather chains, predicated 4-edge tail, packed f32x2
// arithmetic (v_pk_fma_f32), 32-bit gather offsets. [frozen from round 3;
// only change: destructive-offs read convention e0=offs[d-1], e1=offs[d]]
__global__ __launch_bounds__(256) void agg8(
    const unsigned short* __restrict__ Xin,   // [N,256] bf16
    const int* __restrict__ offs,             // post-scatter (shifted)
    const unsigned int* __restrict__ meta,    // packed src<<4|r
    const float* __restrict__ comp,           // [NREL*NBASES] fp32
    const int* __restrict__ cnt_rd,           // [NREL, N]
    unsigned short* __restrict__ z)           // [N, KBASE] bf16
{
  __shared__ __attribute__((aligned(16))) float wtab[4][40];  // [wave][r*4+b]
  int t = threadIdx.x;
  int wv = t >> 6, lane = t & 63;
  int d = blockIdx.x * 4 + wv;
  if (lane < 40){
    int r = lane >> 2, b = lane & 3;
    int cnt = cnt_rd[(r << 15) + d];
    wtab[wv][lane] = (cnt > 0) ? comp[r * NBASES + b] / (float)cnt : 0.0f;
  }
  __syncthreads();

  const float4* wt4 = (const float4*)&wtab[wv][0];   // indexed by r
  const char* Xb = (const char*)Xin;
  unsigned colb = (unsigned)(lane * 8);              // byte offset of this lane's 4 cols

  // acc[b][0] = (col0,col1), acc[b][1] = (col2,col3)
  f32x2 acc[NBASES][2];
#pragma unroll
  for (int b = 0; b < NBASES; b++){ acc[b][0] = (f32x2){0.f,0.f}; acc[b][1] = (f32x2){0.f,0.f}; }

  int e1 = offs[d];
  int e0 = (d == 0) ? 0 : offs[d - 1];
  int e = e0;

  // ---- main: 8 edges per iteration, all gathers issued before consumption
  for (; e + 7 < e1; e += 8){
    unsigned int m[8];
#pragma unroll
    for (int i = 0; i < 8; i++) m[i] = meta[e + i];
    uint2 v[8];
#pragma unroll
    for (int i = 0; i < 8; i++){
      unsigned off = ((m[i] & 0xFFFFFFF0u) << 5) + colb;   // (src*512) + lane*8
      v[i] = *(const uint2*)(Xb + off);
    }
#pragma unroll
    for (int i = 0; i < 8; i++){
      float4 w = wt4[m[i] & 15u];
      f32x2 f01, f23;
      f01.x = asf(v[i].x << 16); f01.y = asf(v[i].x & 0xffff0000u);
      f23.x = asf(v[i].y << 16); f23.y = asf(v[i].y & 0xffff0000u);
      acc[0][0] += (f32x2){w.x, w.x} * f01;  acc[0][1] += (f32x2){w.x, w.x} * f23;
      acc[1][0] += (f32x2){w.y, w.y} * f01;  acc[1][1] += (f32x2){w.y, w.y} * f23;
      acc[2][0] += (f32x2){w.z, w.z} * f01;  acc[2][1] += (f32x2){w.z, w.z} * f23;
      acc[3][0] += (f32x2){w.w, w.w} * f01;  acc[3][1] += (f32x2){w.w, w.w} * f23;
    }
  }

  // ---- tail: predicated 4-edge groups (invalid edges: w=0, index clamped)
  for (; e < e1; e += 4){
    unsigned int m[4];
    float4 w[4];
#pragma unroll
    for (int i = 0; i < 4; i++){
      int ei = e + i;
      bool ok = ei < e1;
      m[i] = meta[ok ? ei : e1 - 1];
      float4 ww = wt4[m[i] & 15u];
      if (!ok){ ww.x = 0.f; ww.y = 0.f; ww.z = 0.f; ww.w = 0.f; }
      w[i] = ww;
    }
    uint2 v[4];
#pragma unroll
    for (int i = 0; i < 4; i++){
      unsigned off = ((m[i] & 0xFFFFFFF0u) << 5) + colb;
      v[i] = *(const uint2*)(Xb + off);
    }
#pragma unroll
    for (int i = 0; i < 4; i++){
      f32x2 f01, f23;
      f01.x = asf(v[i].x << 16); f01.y = asf(v[i].x & 0xffff0000u);
      f23.x = asf(v[i].y << 16); f23.y = asf(v[i].y & 0xffff0000u);
      acc[0][0] += (f32x2){w[i].x, w[i].x} * f01;  acc[0][1] += (f32x2){w[i].x, w[i].x} * f23;
      acc[1][0] += (f32x2){w[i].y, w[i].y} * f01;  acc[1][1] += (f32x2){w[i].y, w[i].y} * f23;
      acc[2][0] += (f32x2){w[i].z, w[i].z} * f01;  acc[2][1] += (f32x2){w[i].z, w[i].z} * f23;
      acc[3][0] += (f32x2){w[i].w, w[i].w} * f01;  acc[3][1] += (f32x2){w[i].w, w[i].w} * f23;
    }
  }

#pragma unroll
  for (int b = 0; b < NBASES; b++){
    ushort4 o;
    o.x = f2bf(acc[b][0].x); o.y = f2bf(acc[b][0].y);
    o.z = f2bf(acc[b][1].x); o.w = f2bf(acc[b][1].y);
    *(ushort4*)(z + (size_t)d * KBASE + b * 256 + lane * 4) = o;
  }
}

// ---- MFMA GEMM v9: Y[M,256] = [z | ext] @ Wt^T + bias
// EXACT m97 geometry (guide: 64-tile=343 TF vs 128-tile=912 TF, measured):
// 128m x 128n tile, BK=32, 4 waves in 2x2 grid (64x64 each), single-buffered
// 16 KB LDS, plain 2-__syncthreads loop, compiler-scheduled, 4 gll16/thread.
// vs gemm4: B traffic per block halved, barrier-drains per unit output halved.
// A/B staging: pre-swizzled global source, linear LDS dst (m173 pattern),
// granule (row, kc) lives at slot (kc + (row>>1)) & 3.
// mode 1: outh = relu(v) bf16 ; mode 2: outf = v fp32
__global__ __launch_bounds__(256) void gemm9(
    const unsigned short* __restrict__ A0,   // z [M,KBASE]
    const unsigned short* __restrict__ A1,   // ext [M,256]
    const unsigned short* __restrict__ Wt,   // [256,KW]
    const float* __restrict__ bias,
    unsigned short* __restrict__ outh,
    float* __restrict__ outf,
    int mode)
{
  __shared__ __attribute__((aligned(16))) short As[128 * 32];   // 8 KB
  __shared__ __attribute__((aligned(16))) short Bs[128 * 32];   // 8 KB
  int tid  = threadIdx.x;
  int bid  = blockIdx.x;
  int m0   = (bid >> 1) * 128;
  int n0   = (bid & 1) * 128;
  int lane = tid & 63;
  int w    = tid >> 6;
  int wm   = w >> 1, wn = w & 1;     // 2x2 wave grid, each wave 64m x 64n
  int lq = lane >> 4, lr = lane & 15;

  f32x4 zero = {0.f, 0.f, 0.f, 0.f};
  f32x4 acc[4][4];
#pragma unroll
  for (int i = 0; i < 4; i++)
#pragma unroll
    for (int j = 0; j < 4; j++) acc[i][j] = zero;

  // staging granules g = tid, tid+256 (512 granules = 128 rows x 4 kc):
  // row = g>>2, slot = g&3, kc = (slot - (row>>1)) & 3 (inverse swizzle)
  int g1   = tid + 256;
  int ar0  = tid >> 2, ak0 = ((tid & 3) - (tid >> 3)) & 3;
  int ar1  = g1 >> 2,  ak1 = ((g1 & 3) - (g1 >> 3)) & 3;

  for (int k0 = 0; k0 < KW; k0 += 32){
    __syncthreads();
    {
      const unsigned short *ga0, *ga1;
      if (k0 < KBASE){
        ga0 = A0 + (size_t)(m0 + ar0) * KBASE + k0 + ak0 * 8;
        ga1 = A0 + (size_t)(m0 + ar1) * KBASE + k0 + ak1 * 8;
      } else {
        ga0 = A1 + (size_t)(m0 + ar0) * 256 + (k0 - KBASE) + ak0 * 8;
        ga1 = A1 + (size_t)(m0 + ar1) * 256 + (k0 - KBASE) + ak1 * 8;
      }
      gll16(ga0, As + tid * 8);
      gll16(ga1, As + g1 * 8);
      gll16(Wt + (size_t)(n0 + ar0) * KW + k0 + ak0 * 8, Bs + tid * 8);
      gll16(Wt + (size_t)(n0 + ar1) * KW + k0 + ak1 * 8, Bs + g1 * 8);
    }
    __syncthreads();

    bf16x8 af[4], bfr[4];
#pragma unroll
    for (int i = 0; i < 4; i++){
      int row = wm * 64 + i * 16 + lr;
      af[i] = *(const bf16x8*)(As + row * 32 + (((lq + (row >> 1)) & 3) * 8));
    }
#pragma unroll
    for (int j = 0; j < 4; j++){
      int row = wn * 64 + j * 16 + lr;
      bfr[j] = *(const bf16x8*)(Bs + row * 32 + (((lq + (row >> 1)) & 3) * 8));
    }
#pragma unroll
    for (int i = 0; i < 4; i++)
#pragma unroll
      for (int j = 0; j < 4; j++)
        acc[i][j] = __builtin_amdgcn_mfma_f32_16x16x32_bf16(af[i], bfr[j], acc[i][j], 0, 0, 0);
  }

  // C/D mapping: col=lane&15, row=(lane>>4)*4+reg  [m89/m91]
#pragma unroll
  for (int i = 0; i < 4; i++)
#pragma unroll
    for (int j = 0; j < 4; j++)
#pragma unroll
      for (int r = 0; r < 4; r++){
        int gm = m0 + wm * 64 + i * 16 + lq * 4 + r;
        int gn = n0 + wn * 64 + j * 16 + lr;
        float v = acc[i][j][r] + bias[gn];
        size_t idx = (size_t)gm * 256 + gn;
        if (mode == 1) outh[idx] = f2bf(fmaxf(v, 0.f));
        else           outf[idx] = v;
      }
}

// ---------------------------------------------------------------------------
extern "C" void kernel_launch(void* const* d_in, const int* in_sizes, int n_in,
                              void* d_out, int out_size, void* d_ws, size_t ws_size,
                              hipStream_t stream)
{
  const float* x      = (const float*)d_in[0];
  const int*   ec     = (const int*)d_in[3];
  const int*   rel    = (const int*)d_in[4];
  const float* basis0 = (const float*)d_in[5];
  const float* comp0  = (const float*)d_in[6];
  const float* root0  = (const float*)d_in[7];
  const float* bias0  = (const float*)d_in[8];
  const float* basis1 = (const float*)d_in[9];
  const float* comp1  = (const float*)d_in[10];
  const float* root1  = (const float*)d_in[11];
  const float* bias1  = (const float*)d_in[12];

  char* p = (char*)d_ws;
  unsigned short* z   = (unsigned short*)p; p += (size_t)NNODES * KBASE * 2;  // 67.1 MB
  unsigned short* Xh  = (unsigned short*)p; p += (size_t)NNODES * DIM * 2;    // 16.8
  unsigned short* h   = (unsigned short*)p; p += (size_t)NNODES * DIM * 2;    // 16.8
  unsigned short* Wt0 = (unsigned short*)p; p += (size_t)256 * KW * 2;        // 0.66
  unsigned short* Wt1 = (unsigned short*)p; p += (size_t)256 * KW * 2;        // 0.66
  unsigned int* meta  = (unsigned int*)p;   p += (size_t)NEDGE * 4;           // 2.1
  int* cnt_rd  = (int*)p;   p += (size_t)NREL * NNODES * 4;                   // 1.3
  int* offs    = (int*)p;   p += (size_t)(NNODES + 1) * 4;
  int* blksum  = (int*)p;   p += 1024;

  // zero cnt_rd (hist accumulator)
  hipMemsetAsync(cnt_rd, 0, (size_t)NREL * NNODES * 4, stream);

  // ---- fused prep: hist | conv | build Wt0 | build Wt1 ----
  mega_prep<<<HB + CB + 2 * WB, 256, 0, stream>>>(
      ec, rel, cnt_rd, x, Xh, basis0, root0, Wt0, basis1, root1, Wt1);

  scan1<<<NNODES / 1024, 1024, 0, stream>>>(cnt_rd, offs, blksum);
  scan3b<<<NNODES / 1024, 1024, 0, stream>>>(offs, blksum);
  scatter_kernel<<<NEDGE / 256, 256, 0, stream>>>(ec, rel, offs, meta);

  // ---- layer 0 ----
  agg8<<<NNODES / 4, 256, 0, stream>>>(Xh, offs, meta, comp0, cnt_rd, z);
  gemm9<<<(NNODES / 128) * 2, 256, 0, stream>>>(z, Xh, Wt0, bias0, h, nullptr, 1);

  // ---- layer 1 ----
  agg8<<<NNODES / 4, 256, 0, stream>>>(h, offs, meta, comp1, cnt_rd, z);
  gemm9<<<(NNODES / 128) * 2, 256, 0, stream>>>(z, h, Wt1, bias1, nullptr, (float*)d_out, 2);
}